// Round 7
// baseline (84.143 us; speedup 1.0000x reference)
//
#include <hip/hip_runtime.h>
#include <hip/hip_bf16.h>

#define N_NODES 50000
#define HDIM    256
#define CDIM    32
#define JDIM    96     // C*3 outputs per node
#define NBLK    32     // nodes per block (32 KB LDS -> 5 blocks/CU resident)
#define KSTEPS  8      // 8 x 32 = 256 K

typedef __attribute__((ext_vector_type(8))) short short8v;  // 8 bf16 = 4 VGPR
typedef __attribute__((ext_vector_type(4))) float f32x4;

// B[h][j] = W1[j%3, h] * W2[h, j/3], stored in MFMA fragment order:
// element idx = ((ks*6 + jt)*64 + lane)*8 + je  ->  k = ks*32 + (lane>>4)*8 + je,
// col = jt*16 + (lane&15).  Split precision: Bh = bf16(B), Bl = bf16(B - Bh).
__device__ short  g_Bh[KSTEPS * 6 * 64 * 8];   // 48 KiB
__device__ short  g_Bl[KSTEPS * 6 * 64 * 8];   // 48 KiB
__device__ float4 g_Zc[HDIM];                  // {b1[h], W1[0,h], W1[1,h], W1[2,h]}

template<bool ISBF>
__device__ __forceinline__ float ldv(const void* __restrict__ p, int i) {
    if constexpr (ISBF) return __bfloat162float(((const __hip_bfloat16*)p)[i]);
    else                return ((const float*)p)[i];
}

// Runtime dtype detection (wave-uniform): bf16 ~N(0,1) has exponent in [100,140].
__device__ __forceinline__ bool detect_bf(const void* pos) {
    unsigned short uw = ((const unsigned short*)pos)[threadIdx.x & 63];
    int ef = (uw >> 7) & 0xFF;
    unsigned long long bal = __ballot(ef >= 100 && ef <= 140);
    return __popcll(bal) >= 56;
}

template<bool ISBF>
__device__ __forceinline__ void build_impl(const void* __restrict__ W1,
                                           const void* __restrict__ b1,
                                           const void* __restrict__ W2) {
    const int idx  = blockIdx.x * 256 + threadIdx.x;   // 0..24575
    const int je   = idx & 7;
    const int lane = (idx >> 3) & 63;
    const int f    = idx >> 9;                         // 0..47
    const int ks   = f / 6, jt = f % 6;
    const int h    = ks * 32 + (lane >> 4) * 8 + je;   // k index (= h)
    const int col  = jt * 16 + (lane & 15);            // j index
    float b = ldv<ISBF>(W1, (col % 3) * HDIM + h) * ldv<ISBF>(W2, h * CDIM + col / 3);
    __hip_bfloat16 hi = __float2bfloat16(b);
    float lo = b - __bfloat162float(hi);
    g_Bh[idx] = (short)__hip_bfloat16_raw(hi).x;
    g_Bl[idx] = (short)__hip_bfloat16_raw(__float2bfloat16(lo)).x;
    if (idx < HDIM) {
        g_Zc[idx] = make_float4(ldv<ISBF>(b1, idx),
                                ldv<ISBF>(W1, 0 * HDIM + idx),
                                ldv<ISBF>(W1, 1 * HDIM + idx),
                                ldv<ISBF>(W1, 2 * HDIM + idx));
    }
}

__global__ __launch_bounds__(256) void build_B(const void* __restrict__ pos,
                                               const void* __restrict__ W1,
                                               const void* __restrict__ b1,
                                               const void* __restrict__ W2) {
    if (detect_bf(pos)) build_impl<true >(W1, b1, W2);
    else                build_impl<false>(W1, b1, W2);
}

// Main kernel. Block = 256 thr = 4 waves, 32 nodes -> 5 blocks/CU resident.
// Phase 1: S = sech^2(z) once per (n,h); TRUNCATION split to bf16 hi/lo
//   (hi = s & 0xFFFF0000, lo = s - hi), packed with v_perm_b32. LDS row =
//   node (512 B), byte offsets XOR-swizzled by ((row&7)<<4) -> phase-2
//   ds_read_b128 lands ~2 lanes/bank-slot (free).
// Phase 2: wave w: m-tile (w>>1)*16, j-half (w&1)*48. Per k-step:
//   2 ds_read_b128 (A hi/lo) + 6 global dwordx4 (B, L2-hot) + 9 MFMA
//   (3-term split, term-major). 5 waves/SIMD hide VMEM/dep latency.
// Swizzle bit 6 collides with the ks*64 immediate -> folded into two base
// pointers (even/odd ks).
template<bool ISBF>
__device__ __forceinline__ void run_impl(
    const void* __restrict__ pos,
    void* __restrict__ out,
    short* __restrict__ SHL)   // [2][32][256] bf16 = 32768 B
{
    const int tid  = threadIdx.x;
    const int lane = tid & 63;
    const int wv   = __builtin_amdgcn_readfirstlane(tid >> 6);  // uniform wave id

    // ---- phase 1: S -> LDS (thread: node = tid&31, 32 h-values) ----
    {
        const int nl = tid & 31;
        const int hg = tid >> 5;                 // 0..7, 32 h each (per-lane ok)
        const int n  = blockIdx.x * NBLK + nl;
        float p0 = 0.f, p1 = 0.f, p2 = 0.f;
        if (n < N_NODES) {
            p0 = ldv<ISBF>(pos, n * 3 + 0);
            p1 = ldv<ISBF>(pos, n * 3 + 1);
            p2 = ldv<ISBF>(pos, n * 3 + 2);
        }
        char* wb = (char*)SHL + nl * 512;
        const unsigned int swz = (unsigned)((nl & 7) << 4);
#pragma unroll 4
        for (int i = 0; i < 32; i += 4) {
            unsigned int hb[4], lb[4];
#pragma unroll
            for (int t = 0; t < 4; ++t) {
                const int h = hg * 32 + i + t;
                float4 zc = g_Zc[h];             // 1 KiB table, L1-hot
                float z   = fmaf(p0, zc.y, fmaf(p1, zc.z, fmaf(p2, zc.w, zc.x)));
                // sech^2(z) = 4u/(1+u)^2, u = e^{-2|z|}: branch-free, no overflow
                float u   = __expf(-2.0f * fabsf(z));
                float inv = __builtin_amdgcn_rcpf(1.0f + u);
                float s   = 4.0f * u * inv * inv;
                hb[t] = __float_as_uint(s) & 0xffff0000u;            // bf16-trunc hi
                lb[t] = __float_as_uint(s - __uint_as_float(hb[t])); // exact residual
            }
            // pack high-16 of pairs: dst = {x1[31:16], x0[31:16]}
            unsigned int ph0 = __builtin_amdgcn_perm(hb[1], hb[0], 0x07060302u);
            unsigned int ph1 = __builtin_amdgcn_perm(hb[3], hb[2], 0x07060302u);
            unsigned int pl0 = __builtin_amdgcn_perm(lb[1], lb[0], 0x07060302u);
            unsigned int pl1 = __builtin_amdgcn_perm(lb[3], lb[2], 0x07060302u);
            const unsigned int off = (unsigned)((hg * 64 + 2 * i)) ^ swz;
            *(uint2*)(wb + off)         = make_uint2(ph0, ph1);   // hi
            *(uint2*)(wb + 16384 + off) = make_uint2(pl0, pl1);   // lo
        }
    }
    __syncthreads();

    // ---- phase 2: MFMA GEMM ----
    const int m0 = (wv >> 1) * 16;     // wave's 16-row m-tile (0 or 16)
    const int jh = wv & 1;             // wave's j-half (0 -> j 0..47, 1 -> 48..95)
    const int arow = m0 + (lane & 15);
    const unsigned int sw   = (unsigned)((arow & 7) << 4);   // bits 4-6
    const unsigned int sw45 = sw & 0x30u;
    const unsigned int sw6  = sw & 0x40u;
    const char* base = (const char*)SHL + arow * 512
                     + (unsigned)(((lane >> 4) * 16) ^ sw45);
    const char* abE = base + sw6;          // even ks: (ks*64)^sw6 = ks*64 + sw6
    const char* abO = base + (64 - sw6);   // odd  ks: (ks*64)^sw6 = (ks-1)*64 + 64 - sw6

    const short8v* __restrict__ Bh = (const short8v*)g_Bh + jh * 192 + lane;
    const short8v* __restrict__ Bl = (const short8v*)g_Bl + jh * 192 + lane;

    f32x4 a0 = {}, a1 = {}, a2 = {};
#pragma unroll
    for (int ks = 0; ks < KSTEPS; ++ks) {
        const char* ap = ((ks & 1) ? abO : abE) + (ks & ~1) * 64;
        short8v ah = *(const short8v*)(ap);            // Shi rows m0..m0+16
        short8v al = *(const short8v*)(ap + 16384);    // Slo
        short8v bh0 = Bh[ks * 384 +   0];
        short8v bh1 = Bh[ks * 384 +  64];
        short8v bh2 = Bh[ks * 384 + 128];
        short8v bl0 = Bl[ks * 384 +   0];
        short8v bl1 = Bl[ks * 384 +  64];
        short8v bl2 = Bl[ks * 384 + 128];
        // term 1: Shi*Bhi
        a0 = __builtin_amdgcn_mfma_f32_16x16x32_bf16(ah, bh0, a0, 0, 0, 0);
        a1 = __builtin_amdgcn_mfma_f32_16x16x32_bf16(ah, bh1, a1, 0, 0, 0);
        a2 = __builtin_amdgcn_mfma_f32_16x16x32_bf16(ah, bh2, a2, 0, 0, 0);
        // term 2: Shi*Blo
        a0 = __builtin_amdgcn_mfma_f32_16x16x32_bf16(ah, bl0, a0, 0, 0, 0);
        a1 = __builtin_amdgcn_mfma_f32_16x16x32_bf16(ah, bl1, a1, 0, 0, 0);
        a2 = __builtin_amdgcn_mfma_f32_16x16x32_bf16(ah, bl2, a2, 0, 0, 0);
        // term 3: Slo*Bhi
        a0 = __builtin_amdgcn_mfma_f32_16x16x32_bf16(al, bh0, a0, 0, 0, 0);
        a1 = __builtin_amdgcn_mfma_f32_16x16x32_bf16(al, bh1, a1, 0, 0, 0);
        a2 = __builtin_amdgcn_mfma_f32_16x16x32_bf16(al, bh2, a2, 0, 0, 0);
    }

    // ---- store: C/D layout col = lane&15, row = (lane>>4)*4 + reg ----
    const int colb = jh * 48 + (lane & 15);
    const int rowb = blockIdx.x * NBLK + m0 + (lane >> 4) * 4;
    f32x4 accs[3] = {a0, a1, a2};
#pragma unroll
    for (int r = 0; r < 4; ++r) {
        const int n = rowb + r;
        if (n >= N_NODES) continue;
#pragma unroll
        for (int jt = 0; jt < 3; ++jt) {
            if constexpr (ISBF) {
                ((unsigned short*)out)[(size_t)n * JDIM + colb + jt * 16] =
                    __hip_bfloat16_raw(__float2bfloat16(accs[jt][r])).x;
            } else {
                ((float*)out)[(size_t)n * JDIM + colb + jt * 16] = accs[jt][r];
            }
        }
    }
}

__global__ __launch_bounds__(256, 5) void grad_fused(
    const void* __restrict__ pos,
    void* __restrict__ out)
{
    __shared__ short SHL[2 * NBLK * 256];   // 32 KiB -> 5 blocks/CU

    if (detect_bf(pos)) run_impl<true >(pos, out, SHL);
    else                run_impl<false>(pos, out, SHL);
}

extern "C" void kernel_launch(void* const* d_in, const int* in_sizes, int n_in,
                              void* d_out, int out_size, void* d_ws, size_t ws_size,
                              hipStream_t stream) {
    (void)d_ws; (void)ws_size; (void)in_sizes; (void)n_in; (void)out_size;
    const void* pos = d_in[0];  // [N,3]
    const void* W1  = d_in[1];  // [3,H]
    const void* b1  = d_in[2];  // [H]
    const void* W2  = d_in[3];  // [H,C]

    // Kernel 1: build split-bf16 B fragments + packed z-coefficients.
    build_B<<<(KSTEPS * 6 * 64 * 8) / 256, 256, 0, stream>>>(pos, W1, b1, W2);

    // Kernel 2: fused sech^2 + MFMA GEMM.
    int grid = (N_NODES + NBLK - 1) / NBLK;  // 1563 blocks
    grad_fused<<<grid, 256, 0, stream>>>(pos, d_out);
}

// Round 8
// 81.643 us; speedup vs baseline: 1.0306x; 1.0306x over previous
//
#include <hip/hip_runtime.h>
#include <hip/hip_bf16.h>

#define N_NODES 50000
#define HDIM    256
#define CDIM    32
#define JDIM    96     // C*3 outputs per node
#define NBLK    32     // nodes per block
#define NTHR    384    // 6 waves: (jt in 0..2) x (kh in 0..1)

typedef __attribute__((ext_vector_type(8)))  short short8v;  // 8 bf16 = 4 VGPR
typedef __attribute__((ext_vector_type(16))) float f32x16;   // 32x32 C/D tile

// B[h,col] = W1[col%3, h] * W2[h, col/3], stored as mfma_f32_32x32x16_bf16
// B-fragments, split precision (hi = RNE bf16(B), lo = bf16(B - hi)).
// idx = ((((kh*8+ks)*2+hilo)*3+jt)*64+lane)*8+e
//   h   = kh*128 + ks*16 + (lane>>5)*8 + e   (k index)
//   col = jt*32 + (lane&31)                  (j index)
__device__ short  g_B[2 * 8 * 2 * 3 * 64 * 8];   // 96 KiB, L2-resident
__device__ float4 g_Zc[HDIM];                    // {b1[h], W1[0,h], W1[1,h], W1[2,h]}

template<bool ISBF>
__device__ __forceinline__ float ldv(const void* __restrict__ p, int i) {
    if constexpr (ISBF) return __bfloat162float(((const __hip_bfloat16*)p)[i]);
    else                return ((const float*)p)[i];
}

// Runtime dtype detection (wave-uniform): bf16 ~N(0,1) has exponent in [100,140].
__device__ __forceinline__ bool detect_bf(const void* pos) {
    unsigned short uw = ((const unsigned short*)pos)[threadIdx.x & 63];
    int ef = (uw >> 7) & 0xFF;
    unsigned long long bal = __ballot(ef >= 100 && ef <= 140);
    return __popcll(bal) >= 56;
}

template<bool ISBF>
__device__ __forceinline__ void build_impl(const void* __restrict__ W1,
                                           const void* __restrict__ b1,
                                           const void* __restrict__ W2) {
    const int idx  = blockIdx.x * 256 + threadIdx.x;   // 0..49151
    const int e    = idx & 7;
    const int lane = (idx >> 3) & 63;
    int t = idx >> 9;
    const int jt   = t % 3;  t /= 3;
    const int hilo = t & 1;  t >>= 1;
    const int ks   = t & 7;
    const int kh   = t >> 3;
    const int h    = kh * 128 + ks * 16 + ((lane >> 5) << 3) + e;
    const int col  = jt * 32 + (lane & 31);
    float b = ldv<ISBF>(W1, (col % 3) * HDIM + h) * ldv<ISBF>(W2, h * CDIM + col / 3);
    __hip_bfloat16 hi = __float2bfloat16(b);
    float lo = b - __bfloat162float(hi);
    g_B[idx] = hilo ? (short)__hip_bfloat16_raw(__float2bfloat16(lo)).x
                    : (short)__hip_bfloat16_raw(hi).x;
    if (idx < HDIM) {
        g_Zc[idx] = make_float4(ldv<ISBF>(b1, idx),
                                ldv<ISBF>(W1, 0 * HDIM + idx),
                                ldv<ISBF>(W1, 1 * HDIM + idx),
                                ldv<ISBF>(W1, 2 * HDIM + idx));
    }
}

__global__ __launch_bounds__(256) void build_B(const void* __restrict__ pos,
                                               const void* __restrict__ W1,
                                               const void* __restrict__ b1,
                                               const void* __restrict__ W2) {
    if (detect_bf(pos)) build_impl<true >(W1, b1, W2);
    else                build_impl<false>(W1, b1, W2);
}

// Main kernel. Block = 384 thr = 6 waves, 32 nodes.
// Phase 1: S = sech^2(z) once per (n,h); truncation split to bf16 hi/lo,
//   packed with v_perm_b32. LDS row = node (512 B), offsets XOR-swizzled
//   by ((row&7)<<4).
// Phase 2: wave (jt, kh) computes C[0..32, jt*32..+32) over K-half kh via
//   mfma_f32_32x32x16_bf16 (16 MAC per B-byte = 2x the 16x16x32 rate ->
//   halves B traffic). Per kstep: 2 ds_read_b128 (A hi/lo, one A-frag
//   feeds all 32 nodes) + 2 global dwordx4 (B hi/lo) + 3 MFMA (hh,hl,lh).
// Reduce: kh=1 waves write partial C to LDS (stride-18 floats -> 2-way
//   banks, free), kh=0 waves add + store.
template<bool ISBF>
__device__ __forceinline__ void run_impl(
    const void* __restrict__ pos,
    void* __restrict__ out,
    short* __restrict__ SHL)   // 32 KiB: hi rows at 0, lo at +16384 B
{
    const int tid  = threadIdx.x;
    const int lane = tid & 63;
    const int wv   = __builtin_amdgcn_readfirstlane(tid >> 6);  // 0..5, uniform
    const int kh   = (wv >= 3) ? 1 : 0;
    const int jt   = wv - 3 * kh;

    // ---- phase 1: S -> LDS; thread (node = tid&31, h-group = tid>>5) ----
    {
        const int nl = tid & 31;
        const int hg = tid >> 5;                 // 0..11
        const int n  = blockIdx.x * NBLK + nl;
        float p0 = 0.f, p1 = 0.f, p2 = 0.f;
        if (n < N_NODES) {
            p0 = ldv<ISBF>(pos, n * 3 + 0);
            p1 = ldv<ISBF>(pos, n * 3 + 1);
            p2 = ldv<ISBF>(pos, n * 3 + 2);
        }
        char* wb = (char*)SHL + nl * 512;
        const unsigned int swz = (unsigned)((nl & 7) << 4);
        // 64 chunks of 4 h over 12 groups (groups 0-3 do 6, 4-11 do 5;
        // trip count uniform within each wave: hg pairs (2w, 2w+1)).
        for (int c = hg; c < 64; c += 12) {
            unsigned int hb[4], lb[4];
#pragma unroll
            for (int t = 0; t < 4; ++t) {
                const int h = c * 4 + t;
                float4 zc = g_Zc[h];             // 4 KiB table, L1-hot
                float z   = fmaf(p0, zc.y, fmaf(p1, zc.z, fmaf(p2, zc.w, zc.x)));
                // sech^2(z) = 4u/(1+u)^2, u = e^{-2|z|}: branch-free, no overflow
                float u   = __expf(-2.0f * fabsf(z));
                float inv = __builtin_amdgcn_rcpf(1.0f + u);
                float s   = 4.0f * u * inv * inv;
                hb[t] = __float_as_uint(s) & 0xffff0000u;            // bf16-trunc hi
                lb[t] = __float_as_uint(s - __uint_as_float(hb[t])); // exact residual
            }
            unsigned int ph0 = __builtin_amdgcn_perm(hb[1], hb[0], 0x07060302u);
            unsigned int ph1 = __builtin_amdgcn_perm(hb[3], hb[2], 0x07060302u);
            unsigned int pl0 = __builtin_amdgcn_perm(lb[1], lb[0], 0x07060302u);
            unsigned int pl1 = __builtin_amdgcn_perm(lb[3], lb[2], 0x07060302u);
            const unsigned int off = (unsigned)(8 * c) ^ swz;   // byte 2h, 8-aligned
            *(uint2*)(wb + off)         = make_uint2(ph0, ph1);   // hi
            *(uint2*)(wb + 16384 + off) = make_uint2(pl0, pl1);   // lo
        }
    }
    __syncthreads();

    // ---- phase 2: MFMA GEMM (A: row = lane&31, k = ks*16 + (lane>>5)*8+e) ----
    const int arow = lane & 31;
    const unsigned int sw = (unsigned)((arow & 7) << 4);   // swizzle bits 4-6
    const char* base = (const char*)SHL + arow * 512 + kh * 256
                     + (unsigned)(((lane >> 5) * 16) ^ (sw & 0x10u));
    // (ks*32)^sw[5:6] = ((ks&3)*32 ^ sw56) + (ks>>2)*128
    const char* pAs[4] = { base + ((0u * 32) ^ (sw & 0x60u)),
                           base + ((1u * 32) ^ (sw & 0x60u)),
                           base + ((2u * 32) ^ (sw & 0x60u)),
                           base + ((3u * 32) ^ (sw & 0x60u)) };
    const short8v* __restrict__ Bb =
        (const short8v*)g_B + (kh * 48 + jt) * 64 + lane;   // frag(kh,ks=0,hi,jt)

    f32x16 acc = {};
#pragma unroll
    for (int ks = 0; ks < 8; ++ks) {
        const char* ap = pAs[ks & 3] + (ks >> 2) * 128;
        short8v ah = *(const short8v*)(ap);            // Shi, all 32 rows
        short8v al = *(const short8v*)(ap + 16384);    // Slo
        short8v bh = Bb[ks * 384];                     // Bhi
        short8v bl = Bb[ks * 384 + 192];               // Blo
        acc = __builtin_amdgcn_mfma_f32_32x32x16_bf16(ah, bh, acc, 0, 0, 0);
        acc = __builtin_amdgcn_mfma_f32_32x32x16_bf16(ah, bl, acc, 0, 0, 0);
        acc = __builtin_amdgcn_mfma_f32_32x32x16_bf16(al, bh, acc, 0, 0, 0);
    }

    // ---- reduce K-halves through LDS (reuse S region), then store ----
    __syncthreads();                       // all waves done reading S
    float* red = (float*)SHL;              // [jt*64+lane] rows, stride 18 floats
    if (kh == 1) {
        float* rp = red + (jt * 64 + lane) * 18;
#pragma unroll
        for (int r = 0; r < 16; r += 2)
            *(float2*)(rp + r) = make_float2(acc[r], acc[r + 1]);  // 2-way banks
    }
    __syncthreads();
    if (kh == 0) {
        const float* rp = red + (jt * 64 + lane) * 18;
#pragma unroll
        for (int r = 0; r < 16; r += 2) {
            float2 p = *(const float2*)(rp + r);
            acc[r] += p.x; acc[r + 1] += p.y;
        }
        // C/D layout (32x32): col = lane&31, row = (r&3) + 8*(r>>2) + 4*(lane>>5)
        const int colb  = jt * 32 + (lane & 31);
        const int rbase = blockIdx.x * NBLK + 4 * (lane >> 5);
#pragma unroll
        for (int r = 0; r < 16; ++r) {
            const int n = rbase + (r & 3) + 8 * (r >> 2);
            if (n >= N_NODES) continue;
            if constexpr (ISBF) {
                ((unsigned short*)out)[(size_t)n * JDIM + colb] =
                    __hip_bfloat16_raw(__float2bfloat16(acc[r])).x;
            } else {
                ((float*)out)[(size_t)n * JDIM + colb] = acc[r];
            }
        }
    }
}

__global__ __launch_bounds__(NTHR, 7) void grad_fused(
    const void* __restrict__ pos,
    void* __restrict__ out)
{
    __shared__ short SHL[2 * NBLK * 256];   // 32 KiB

    if (detect_bf(pos)) run_impl<true >(pos, out, SHL);
    else                run_impl<false>(pos, out, SHL);
}

extern "C" void kernel_launch(void* const* d_in, const int* in_sizes, int n_in,
                              void* d_out, int out_size, void* d_ws, size_t ws_size,
                              hipStream_t stream) {
    (void)d_ws; (void)ws_size; (void)in_sizes; (void)n_in; (void)out_size;
    const void* pos = d_in[0];  // [N,3]
    const void* W1  = d_in[1];  // [3,H]
    const void* b1  = d_in[2];  // [H]
    const void* W2  = d_in[3];  // [H,C]

    // Kernel 1: build split-bf16 B fragments (32x32 layout) + z-coefficients.
    build_B<<<(2 * 8 * 2 * 3 * 64 * 8) / 256, 256, 0, stream>>>(pos, W1, b1, W2);

    // Kernel 2: fused sech^2 + MFMA GEMM.
    int grid = (N_NODES + NBLK - 1) / NBLK;  // 1563 blocks
    grad_fused<<<grid, NTHR, 0, stream>>>(pos, d_out);
}